// Round 1
// baseline (2259.927 us; speedup 1.0000x reference)
//
#include <hip/hip_runtime.h>
#include <math.h>

constexpr int NN     = 100000;
constexpr int E_BASE = 1600000;
constexpr int E_TOT  = E_BASE + NN;   // 1,700,000 (self-loops appended)
constexpr int F_IN   = 128;
constexpr int F1     = 64;            // H1*C1
constexpr int H1n    = 8;
constexpr int F2     = 40;            // layer-2 out (H=1)
__device__ __forceinline__ float lrelu(float v) { return v > 0.f ? v : 0.2f * v; }

// order-preserving float<->uint encoding for atomicMax on floats
__device__ __forceinline__ unsigned fenc(float f) {
    unsigned b = __float_as_uint(f);
    return (b & 0x80000000u) ? ~b : (b | 0x80000000u);
}
__device__ __forceinline__ float fdec(unsigned e) {
    unsigned b = (e & 0x80000000u) ? (e ^ 0x80000000u) : ~e;
    return __uint_as_float(b);
}

__device__ __forceinline__ void edge_nodes(int e, const int* __restrict__ src,
                                           const int* __restrict__ dst, int& s, int& d) {
    if (e < E_BASE) { s = src[e]; d = dst[e]; }
    else            { s = e - E_BASE; d = s; }
}

// ---- layer 1: h1 = x @ W1, alpha logits per node -------------------------
__global__ void linear1(const float* __restrict__ x, const float* __restrict__ W1,
                        const float* __restrict__ a_src, const float* __restrict__ a_dst,
                        float* __restrict__ h1, float* __restrict__ as1,
                        float* __restrict__ ad1) {
    int n = blockIdx.x;
    int c = threadIdx.x;             // 0..63
    __shared__ float xs[F_IN];
    xs[c]      = x[n * F_IN + c];
    xs[c + 64] = x[n * F_IN + 64 + c];
    __syncthreads();
    float acc = 0.f;
#pragma unroll 8
    for (int k = 0; k < F_IN; ++k) acc = fmaf(xs[k], W1[k * F1 + c], acc);
    h1[n * F1 + c] = acc;
    int h = c >> 3, cc = c & 7;
    float vs = acc * a_src[h * 8 + cc];
    float vd = acc * a_dst[h * 8 + cc];
#pragma unroll
    for (int m = 1; m < 8; m <<= 1) { vs += __shfl_xor(vs, m, 8); vd += __shfl_xor(vd, m, 8); }
    if (cc == 0) { as1[n * H1n + h] = vs; ad1[n * H1n + h] = vd; }
}

__global__ void edge_max1(const int* __restrict__ src, const int* __restrict__ dst,
                          const float* __restrict__ as1, const float* __restrict__ ad1,
                          unsigned* __restrict__ emax) {
    int e = blockIdx.x * blockDim.x + threadIdx.x;
    if (e >= E_TOT) return;
    int s, d; edge_nodes(e, src, dst, s, d);
#pragma unroll
    for (int h = 0; h < H1n; ++h) {
        float v = lrelu(as1[s * H1n + h] + ad1[d * H1n + h]);
        atomicMax(&emax[d * H1n + h], fenc(v));
    }
}

__global__ void edge_denom1(const int* __restrict__ src, const int* __restrict__ dst,
                            const float* __restrict__ as1, const float* __restrict__ ad1,
                            const unsigned* __restrict__ emax, float* __restrict__ denom) {
    int e = blockIdx.x * blockDim.x + threadIdx.x;
    if (e >= E_TOT) return;
    int s, d; edge_nodes(e, src, dst, s, d);
#pragma unroll
    for (int h = 0; h < H1n; ++h) {
        float v = lrelu(as1[s * H1n + h] + ad1[d * H1n + h]);
        atomicAdd(&denom[d * H1n + h], expf(v - fdec(emax[d * H1n + h])));
    }
}

// wave per edge; lane = output channel (64 = H1*C1)
__global__ void edge_agg1(const int* __restrict__ src, const int* __restrict__ dst,
                          const float* __restrict__ as1, const float* __restrict__ ad1,
                          const unsigned* __restrict__ emax, const float* __restrict__ denom,
                          const float* __restrict__ h1, float* __restrict__ out1) {
    long long t = (long long)blockIdx.x * blockDim.x + threadIdx.x;
    int e = (int)(t >> 6);
    if (e >= E_TOT) return;
    int lane = (int)(t & 63);
    int s, d; edge_nodes(e, src, dst, s, d);
    int h = lane >> 3;
    float v = lrelu(as1[s * H1n + h] + ad1[d * H1n + h]);
    float alpha = expf(v - fdec(emax[d * H1n + h])) / (denom[d * H1n + h] + 1e-16f);
    atomicAdd(&out1[d * F1 + lane], h1[s * F1 + lane] * alpha);
}

// ---- layer 2: h2 = relu(out1+b1) @ W2, logits ----------------------------
__global__ void linear2(const float* __restrict__ out1, const float* __restrict__ b1,
                        const float* __restrict__ W2, const float* __restrict__ a_src2,
                        const float* __restrict__ a_dst2, float* __restrict__ h2,
                        float* __restrict__ as2, float* __restrict__ ad2) {
    int n = blockIdx.x;
    int i = threadIdx.x;             // 0..63
    __shared__ float hs[F1];
    float t = out1[n * F1 + i] + b1[i];
    hs[i] = t > 0.f ? t : 0.f;
    __syncthreads();
    float vs = 0.f, vd = 0.f;
    if (i < F2) {
        float acc = 0.f;
#pragma unroll 8
        for (int k = 0; k < F1; ++k) acc = fmaf(hs[k], W2[k * F2 + i], acc);
        h2[n * F2 + i] = acc;
        vs = acc * a_src2[i];
        vd = acc * a_dst2[i];
    }
#pragma unroll
    for (int m = 1; m < 64; m <<= 1) { vs += __shfl_xor(vs, m, 64); vd += __shfl_xor(vd, m, 64); }
    if (i == 0) { as2[n] = vs; ad2[n] = vd; }
}

__global__ void edge_max2(const int* __restrict__ src, const int* __restrict__ dst,
                          const float* __restrict__ as2, const float* __restrict__ ad2,
                          unsigned* __restrict__ emax) {
    int e = blockIdx.x * blockDim.x + threadIdx.x;
    if (e >= E_TOT) return;
    int s, d; edge_nodes(e, src, dst, s, d);
    float v = lrelu(as2[s] + ad2[d]);
    atomicMax(&emax[d], fenc(v));
}

__global__ void edge_denom2(const int* __restrict__ src, const int* __restrict__ dst,
                            const float* __restrict__ as2, const float* __restrict__ ad2,
                            const unsigned* __restrict__ emax, float* __restrict__ denom) {
    int e = blockIdx.x * blockDim.x + threadIdx.x;
    if (e >= E_TOT) return;
    int s, d; edge_nodes(e, src, dst, s, d);
    float v = lrelu(as2[s] + ad2[d]);
    atomicAdd(&denom[d], expf(v - fdec(emax[d])));
}

// wave per edge; lanes 0..39 carry channels
__global__ void edge_agg2(const int* __restrict__ src, const int* __restrict__ dst,
                          const float* __restrict__ as2, const float* __restrict__ ad2,
                          const unsigned* __restrict__ emax, const float* __restrict__ denom,
                          const float* __restrict__ h2, float* __restrict__ out) {
    long long t = (long long)blockIdx.x * blockDim.x + threadIdx.x;
    int e = (int)(t >> 6);
    if (e >= E_TOT) return;
    int lane = (int)(t & 63);
    int s, d; edge_nodes(e, src, dst, s, d);
    float v = lrelu(as2[s] + ad2[d]);
    float alpha = expf(v - fdec(emax[d])) / (denom[d] + 1e-16f);
    if (lane < F2) atomicAdd(&out[d * F2 + lane], h2[s * F2 + lane] * alpha);
}

__global__ void bias_add(float* __restrict__ out, const float* __restrict__ b2) {
    int i = blockIdx.x * blockDim.x + threadIdx.x;
    if (i < NN * F2) out[i] += b2[i % F2];
}

extern "C" void kernel_launch(void* const* d_in, const int* in_sizes, int n_in,
                              void* d_out, int out_size, void* d_ws, size_t ws_size,
                              hipStream_t stream) {
    const float* x      = (const float*)d_in[0];
    const int*   ei     = (const int*)d_in[1];
    const float* W1     = (const float*)d_in[2];
    const float* a_src1 = (const float*)d_in[3];
    const float* a_dst1 = (const float*)d_in[4];
    const float* b1     = (const float*)d_in[5];
    const float* W2     = (const float*)d_in[6];
    const float* a_src2 = (const float*)d_in[7];
    const float* a_dst2 = (const float*)d_in[8];
    const float* b2     = (const float*)d_in[9];
    float* out = (float*)d_out;
    const int* srcp = ei;            // edge_index[0]
    const int* dstp = ei + E_BASE;   // edge_index[1]

    float* ws = (float*)d_ws;
    float*    h1     = ws;                       // N*64
    float*    as1    = h1 + (size_t)NN * F1;     // N*8
    float*    ad1    = as1 + (size_t)NN * H1n;   // N*8
    unsigned* emax1  = (unsigned*)(ad1 + (size_t)NN * H1n);  // N*8
    float*    denom1 = (float*)(emax1 + (size_t)NN * H1n);   // N*8
    float*    out1   = denom1 + (size_t)NN * H1n;            // N*64
    float*    h2     = out1 + (size_t)NN * F1;               // N*40
    float*    as2    = h2 + (size_t)NN * F2;                 // N
    float*    ad2    = as2 + NN;                              // N
    unsigned* emax2  = (unsigned*)(ad2 + NN);                 // N
    float*    denom2 = (float*)(emax2 + NN);                  // N

    hipMemsetAsync(emax1, 0, (size_t)NN * H1n * 4, stream);
    hipMemsetAsync(denom1, 0, (size_t)NN * H1n * 4, stream);
    hipMemsetAsync(out1, 0, (size_t)NN * F1 * 4, stream);
    hipMemsetAsync(emax2, 0, (size_t)NN * 4, stream);
    hipMemsetAsync(denom2, 0, (size_t)NN * 4, stream);
    hipMemsetAsync(out, 0, (size_t)out_size * 4, stream);

    linear1<<<NN, 64, 0, stream>>>(x, W1, a_src1, a_dst1, h1, as1, ad1);

    int eb = (E_TOT + 255) / 256;
    edge_max1<<<eb, 256, 0, stream>>>(srcp, dstp, as1, ad1, emax1);
    edge_denom1<<<eb, 256, 0, stream>>>(srcp, dstp, as1, ad1, emax1, denom1);
    int wb = (int)(((long long)E_TOT * 64 + 255) / 256);
    edge_agg1<<<wb, 256, 0, stream>>>(srcp, dstp, as1, ad1, emax1, denom1, h1, out1);

    linear2<<<NN, 64, 0, stream>>>(out1, b1, W2, a_src2, a_dst2, h2, as2, ad2);

    edge_max2<<<eb, 256, 0, stream>>>(srcp, dstp, as2, ad2, emax2);
    edge_denom2<<<eb, 256, 0, stream>>>(srcp, dstp, as2, ad2, emax2, denom2);
    edge_agg2<<<wb, 256, 0, stream>>>(srcp, dstp, as2, ad2, emax2, denom2, h2, out);

    bias_add<<<(NN * F2 + 255) / 256, 256, 0, stream>>>(out, b2);
}

// Round 2
// 761.549 us; speedup vs baseline: 2.9675x; 2.9675x over previous
//
#include <hip/hip_runtime.h>
#include <math.h>

constexpr int NN     = 100000;
constexpr int E_BASE = 1600000;
constexpr int E_TOT  = E_BASE + NN;   // self-loops appended
constexpr int F_IN   = 128;
constexpr int F1     = 64;            // H1*C1
constexpr int H1n    = 8;
constexpr int F2     = 40;            // layer-2 out (H=1)

__device__ __forceinline__ float lrelu(float v) { return v > 0.f ? v : 0.2f * v; }

// ---- CSR build (by dst) --------------------------------------------------
__global__ void count_deg(const int* __restrict__ dst, int* __restrict__ deg) {
    int e = blockIdx.x * blockDim.x + threadIdx.x;
    if (e >= E_TOT) return;
    int d = (e < E_BASE) ? dst[e] : (e - E_BASE);
    atomicAdd(&deg[d], 1);
}

// single block, 1024 threads: chunked serial + Hillis-Steele block scan
__global__ void scan_deg(const int* __restrict__ deg, int* __restrict__ row_start) {
    __shared__ int part[1024];
    int t = threadIdx.x;
    const int CH = (NN + 1023) / 1024;
    int lo = t * CH, hi = min(lo + CH, NN);
    if (lo > NN) lo = NN;
    if (hi < lo) hi = lo;
    int s = 0;
    for (int i = lo; i < hi; ++i) s += deg[i];
    part[t] = s;
    __syncthreads();
    for (int off = 1; off < 1024; off <<= 1) {
        int v = (t >= off) ? part[t - off] : 0;
        __syncthreads();
        part[t] += v;
        __syncthreads();
    }
    int base = (t == 0) ? 0 : part[t - 1];
    for (int i = lo; i < hi; ++i) { row_start[i] = base; base += deg[i]; }
    if (t == 1023) row_start[NN] = part[1023];
}

__global__ void scatter_csr(const int* __restrict__ src, const int* __restrict__ dst,
                            const int* __restrict__ row_start, int* __restrict__ cursor,
                            int* __restrict__ csr_src) {
    int e = blockIdx.x * blockDim.x + threadIdx.x;
    if (e >= E_TOT) return;
    int s, d;
    if (e < E_BASE) { s = src[e]; d = dst[e]; }
    else            { s = e - E_BASE; d = s; }
    int pos = atomicAdd(&cursor[d], 1);
    csr_src[row_start[d] + pos] = s;
}

// ---- layer 1 linear: h1 = x @ W1, per-node logits ------------------------
__global__ void linear1(const float* __restrict__ x, const float* __restrict__ W1,
                        const float* __restrict__ a_src, const float* __restrict__ a_dst,
                        float* __restrict__ h1, float* __restrict__ as1,
                        float* __restrict__ ad1) {
    int n = blockIdx.x;
    int c = threadIdx.x;             // 0..63
    __shared__ float xs[F_IN];
    xs[c]      = x[n * F_IN + c];
    xs[c + 64] = x[n * F_IN + 64 + c];
    __syncthreads();
    float acc = 0.f;
#pragma unroll 8
    for (int k = 0; k < F_IN; ++k) acc = fmaf(xs[k], W1[k * F1 + c], acc);
    h1[n * F1 + c] = acc;
    int h = c >> 3, cc = c & 7;
    float vs = acc * a_src[h * 8 + cc];
    float vd = acc * a_dst[h * 8 + cc];
#pragma unroll
    for (int m = 1; m < 8; m <<= 1) { vs += __shfl_xor(vs, m, 8); vd += __shfl_xor(vd, m, 8); }
    if (cc == 0) { as1[n * H1n + h] = vs; ad1[n * H1n + h] = vd; }
}

// ---- layer 1 softmax+aggregate, one block (=1 wave) per dst node ---------
// lane = output channel (64); head = lane>>3; online softmax per head.
// Fuses +b1 and relu (layer-2 input is relu(out+b1)).
__global__ void node_agg1(const int* __restrict__ row_start, const int* __restrict__ csr_src,
                          const float* __restrict__ as1, const float* __restrict__ ad1,
                          const float* __restrict__ h1, const float* __restrict__ b1,
                          float* __restrict__ out1r) {
    int n = blockIdx.x;
    int lane = threadIdx.x;          // 0..63
    int h = lane >> 3;
    float adv = ad1[n * H1n + h];
    float m = -1e30f, ssum = 0.f, acc = 0.f;
    int lo = row_start[n], hi = row_start[n + 1];
    for (int i = lo; i < hi; ++i) {
        int s = csr_src[i];
        float v = lrelu(as1[s * H1n + h] + adv);
        float newm = fmaxf(m, v);
        float scale = expf(m - newm);
        float p = expf(v - newm);
        ssum = ssum * scale + p;
        acc  = acc  * scale + p * h1[s * F1 + lane];
        m = newm;
    }
    float o = acc / (ssum + 1e-16f) + b1[lane];
    out1r[n * F1 + lane] = o > 0.f ? o : 0.f;
}

// ---- layer 2 linear: h2 = out1r @ W2, logits -----------------------------
__global__ void linear2(const float* __restrict__ out1r, const float* __restrict__ W2,
                        const float* __restrict__ a_src2, const float* __restrict__ a_dst2,
                        float* __restrict__ h2, float* __restrict__ as2,
                        float* __restrict__ ad2) {
    int n = blockIdx.x;
    int i = threadIdx.x;             // 0..63
    __shared__ float hs[F1];
    hs[i] = out1r[n * F1 + i];
    __syncthreads();
    float vs = 0.f, vd = 0.f;
    if (i < F2) {
        float acc = 0.f;
#pragma unroll 8
        for (int k = 0; k < F1; ++k) acc = fmaf(hs[k], W2[k * F2 + i], acc);
        h2[n * F2 + i] = acc;
        vs = acc * a_src2[i];
        vd = acc * a_dst2[i];
    }
#pragma unroll
    for (int m = 1; m < 64; m <<= 1) { vs += __shfl_xor(vs, m, 64); vd += __shfl_xor(vd, m, 64); }
    if (i == 0) { as2[n] = vs; ad2[n] = vd; }
}

// ---- layer 2 softmax+aggregate (+b2), one wave per node ------------------
__global__ void node_agg2(const int* __restrict__ row_start, const int* __restrict__ csr_src,
                          const float* __restrict__ as2, const float* __restrict__ ad2,
                          const float* __restrict__ h2, const float* __restrict__ b2,
                          float* __restrict__ out) {
    int n = blockIdx.x;
    int lane = threadIdx.x;          // 0..63; 0..39 carry channels
    float adv = ad2[n];
    float m = -1e30f, ssum = 0.f, acc = 0.f;
    int lo = row_start[n], hi = row_start[n + 1];
    for (int i = lo; i < hi; ++i) {
        int s = csr_src[i];
        float v = lrelu(as2[s] + adv);
        float newm = fmaxf(m, v);
        float scale = expf(m - newm);
        float p = expf(v - newm);
        ssum = ssum * scale + p;
        if (lane < F2) acc = acc * scale + p * h2[s * F2 + lane];
        m = newm;
    }
    if (lane < F2) out[n * F2 + lane] = acc / (ssum + 1e-16f) + b2[lane];
}

extern "C" void kernel_launch(void* const* d_in, const int* in_sizes, int n_in,
                              void* d_out, int out_size, void* d_ws, size_t ws_size,
                              hipStream_t stream) {
    const float* x      = (const float*)d_in[0];
    const int*   ei     = (const int*)d_in[1];
    const float* W1     = (const float*)d_in[2];
    const float* a_src1 = (const float*)d_in[3];
    const float* a_dst1 = (const float*)d_in[4];
    const float* b1     = (const float*)d_in[5];
    const float* W2     = (const float*)d_in[6];
    const float* a_src2 = (const float*)d_in[7];
    const float* a_dst2 = (const float*)d_in[8];
    const float* b2     = (const float*)d_in[9];
    float* out = (float*)d_out;
    const int* srcp = ei;            // edge_index[0]
    const int* dstp = ei + E_BASE;   // edge_index[1]

    // workspace layout (floats unless noted). deg/cursor alias h1's region:
    // CSR build completes before linear1 overwrites h1.
    float* ws = (float*)d_ws;
    float* h1        = ws;                                   // N*64
    float* as1       = h1 + (size_t)NN * F1;                 // N*8
    float* ad1       = as1 + (size_t)NN * H1n;               // N*8
    float* out1r     = ad1 + (size_t)NN * H1n;               // N*64
    float* h2        = out1r + (size_t)NN * F1;              // N*40
    float* as2       = h2 + (size_t)NN * F2;                 // N
    float* ad2       = as2 + NN;                             // N
    int*   row_start = (int*)(ad2 + NN);                     // N+1 ints
    int*   csr_src   = row_start + (NN + 1);                 // E_TOT ints
    int*   deg       = (int*)h1;                             // N ints (aliased)
    int*   cursor    = deg + NN;                             // N ints (aliased)

    hipMemsetAsync(deg, 0, 2 * (size_t)NN * sizeof(int), stream);  // deg+cursor

    int eb = (E_TOT + 255) / 256;
    count_deg<<<eb, 256, 0, stream>>>(dstp, deg);
    scan_deg<<<1, 1024, 0, stream>>>(deg, row_start);
    scatter_csr<<<eb, 256, 0, stream>>>(srcp, dstp, row_start, cursor, csr_src);

    linear1<<<NN, 64, 0, stream>>>(x, W1, a_src1, a_dst1, h1, as1, ad1);
    node_agg1<<<NN, 64, 0, stream>>>(row_start, csr_src, as1, ad1, h1, b1, out1r);

    linear2<<<NN, 64, 0, stream>>>(out1r, W2, a_src2, a_dst2, h2, as2, ad2);
    node_agg2<<<NN, 64, 0, stream>>>(row_start, csr_src, as2, ad2, h2, b2, out);
}

// Round 3
// 594.220 us; speedup vs baseline: 3.8032x; 1.2816x over previous
//
#include <hip/hip_runtime.h>
#include <math.h>

constexpr int NN     = 100000;
constexpr int E_BASE = 1600000;
constexpr int E_TOT  = E_BASE + NN;   // self-loops appended
constexpr int F_IN   = 128;
constexpr int F1     = 64;            // H1*C1
constexpr int H1n    = 8;
constexpr int F2     = 40;            // layer-2 out (H=1)

__device__ __forceinline__ float lrelu(float v) { return fmaxf(v, 0.2f * v); }

// ---------------- CSR build (by dst) ----------------
__global__ void count_deg(const int* __restrict__ dst, int* __restrict__ deg) {
    int e = blockIdx.x * blockDim.x + threadIdx.x;
    if (e >= E_TOT) return;
    int d = (e < E_BASE) ? dst[e] : (e - E_BASE);
    atomicAdd(&deg[d], 1);
}

__global__ void scan_deg(const int* __restrict__ deg, int* __restrict__ row_start) {
    __shared__ int part[1024];
    int t = threadIdx.x;
    const int CH = (NN + 1023) / 1024;
    int lo = min(t * CH, NN), hi = min(lo + CH, NN);
    int s = 0;
    for (int i = lo; i < hi; ++i) s += deg[i];
    part[t] = s;
    __syncthreads();
    for (int off = 1; off < 1024; off <<= 1) {
        int v = (t >= off) ? part[t - off] : 0;
        __syncthreads();
        part[t] += v;
        __syncthreads();
    }
    int base = (t == 0) ? 0 : part[t - 1];
    for (int i = lo; i < hi; ++i) { row_start[i] = base; base += deg[i]; }
    if (t == 1023) row_start[NN] = part[1023];
}

__global__ void scatter_csr(const int* __restrict__ src, const int* __restrict__ dst,
                            const int* __restrict__ row_start, int* __restrict__ cursor,
                            int* __restrict__ csr_src) {
    int e = blockIdx.x * blockDim.x + threadIdx.x;
    if (e >= E_TOT) return;
    int s, d;
    if (e < E_BASE) { s = src[e]; d = dst[e]; }
    else            { s = e - E_BASE; d = s; }
    int pos = atomicAdd(&cursor[d], 1);
    csr_src[row_start[d] + pos] = s;
}

// ---------------- layer 1 GEMM: h1 = x @ W1 (tiled) ----------------
// 64 nodes/block, 256 threads, 4x4 register tile, K-steps of 32.
__global__ __launch_bounds__(256) void linear1(const float* __restrict__ x,
                                               const float* __restrict__ W1,
                                               float* __restrict__ h1) {
    __shared__ float xs[64][36];      // padded: bank-even
    __shared__ float ws[32 * 64];     // contiguous W1 K-tile
    int t = threadIdx.x;
    int nb = blockIdx.x * 64;
    int ct = t & 15, nt = t >> 4;     // c0 = ct*4, n0 = nt*4
    int rs = t >> 3, qs = t & 7;      // staging: rows rs, rs+32; float4-col qs
    float acc[4][4] = {};
    for (int K0 = 0; K0 < F_IN; K0 += 32) {
        int r0 = min(nb + rs, NN - 1);
        int r1 = min(nb + rs + 32, NN - 1);
        float4 v0 = *(const float4*)&x[(size_t)r0 * F_IN + K0 + qs * 4];
        float4 v1 = *(const float4*)&x[(size_t)r1 * F_IN + K0 + qs * 4];
        *(float4*)&xs[rs][qs * 4] = v0;
        *(float4*)&xs[rs + 32][qs * 4] = v1;
        const float4* wsrc = (const float4*)&W1[(size_t)K0 * F1];
        *(float4*)&ws[t * 4] = wsrc[t];
        *(float4*)&ws[1024 + t * 4] = wsrc[256 + t];
        __syncthreads();
#pragma unroll 8
        for (int kk = 0; kk < 32; ++kk) {
            float4 w = *(const float4*)&ws[kk * 64 + ct * 4];
            float x0 = xs[nt * 4 + 0][kk];
            float x1 = xs[nt * 4 + 1][kk];
            float x2 = xs[nt * 4 + 2][kk];
            float x3 = xs[nt * 4 + 3][kk];
            acc[0][0] = fmaf(x0, w.x, acc[0][0]); acc[0][1] = fmaf(x0, w.y, acc[0][1]);
            acc[0][2] = fmaf(x0, w.z, acc[0][2]); acc[0][3] = fmaf(x0, w.w, acc[0][3]);
            acc[1][0] = fmaf(x1, w.x, acc[1][0]); acc[1][1] = fmaf(x1, w.y, acc[1][1]);
            acc[1][2] = fmaf(x1, w.z, acc[1][2]); acc[1][3] = fmaf(x1, w.w, acc[1][3]);
            acc[2][0] = fmaf(x2, w.x, acc[2][0]); acc[2][1] = fmaf(x2, w.y, acc[2][1]);
            acc[2][2] = fmaf(x2, w.z, acc[2][2]); acc[2][3] = fmaf(x2, w.w, acc[2][3]);
            acc[3][0] = fmaf(x3, w.x, acc[3][0]); acc[3][1] = fmaf(x3, w.y, acc[3][1]);
            acc[3][2] = fmaf(x3, w.z, acc[3][2]); acc[3][3] = fmaf(x3, w.w, acc[3][3]);
        }
        __syncthreads();
    }
#pragma unroll
    for (int i = 0; i < 4; ++i) {
        int n = nb + nt * 4 + i;
        if (n < NN) {
            float4 o = make_float4(acc[i][0], acc[i][1], acc[i][2], acc[i][3]);
            *(float4*)&h1[(size_t)n * F1 + ct * 4] = o;
        }
    }
}

// ---------------- layer 1 logits: thread per (node, head) ----------------
__global__ void logits1(const float* __restrict__ h1, const float* __restrict__ a_src,
                        const float* __restrict__ a_dst, float* __restrict__ as1,
                        float* __restrict__ ad1) {
    int t = blockIdx.x * 256 + threadIdx.x;     // t = n*8 + h
    if (t >= NN * H1n) return;
    int h = t & 7;
    const float4* hp = (const float4*)&h1[(size_t)t * 8];   // n*64 + h*8 == t*8
    float4 u0 = hp[0], u1 = hp[1];
    const float4* ap = (const float4*)&a_src[h * 8];
    const float4* dp = (const float4*)&a_dst[h * 8];
    float4 a0 = ap[0], a1 = ap[1], d0 = dp[0], d1 = dp[1];
    float vs = u0.x * a0.x + u0.y * a0.y + u0.z * a0.z + u0.w * a0.w
             + u1.x * a1.x + u1.y * a1.y + u1.z * a1.z + u1.w * a1.w;
    float vd = u0.x * d0.x + u0.y * d0.y + u0.z * d0.z + u0.w * d0.w
             + u1.x * d1.x + u1.y * d1.y + u1.z * d1.z + u1.w * d1.w;
    as1[t] = vs;
    ad1[t] = vd;
}

// ---------------- layer 1 softmax+aggregate ----------------
// 1 wave/node. p-phase: lane=(head<<3)|e over 8-edge chunks; acc-phase: lane=channel.
// Max-free softmax (logits are O(1); exp(v)/sum identical to max-subtracted form).
__global__ void node_agg1(const int* __restrict__ row_start, const int* __restrict__ csr_src,
                          const float* __restrict__ as1, const float* __restrict__ ad1,
                          const float* __restrict__ h1, const float* __restrict__ b1,
                          float* __restrict__ out1r) {
    int n = blockIdx.x;
    int lane = threadIdx.x;          // channel c; head = lane>>3 (both phases)
    float adv = ad1[n * H1n + (lane >> 3)];
    int lo = row_start[n], hi = row_start[n + 1];
    float ssum = 0.f, acc = 0.f;
    for (int base = lo; base < hi; base += 8) {
        int idx = base + (lane & 7);
        bool valid = idx < hi;
        int s = csr_src[valid ? idx : (hi - 1)];
        float v = lrelu(as1[s * H1n + (lane >> 3)] + adv);
        float p = valid ? __expf(v) : 0.f;
        ssum += p;
        int cnt = min(hi - base, 8);
        for (int e = 0; e < cnt; ++e) {
            int   sb = __shfl(s, e, 64);
            float pb = __shfl(p, (lane & 56) | e, 64);
            acc = fmaf(pb, h1[(size_t)sb * F1 + lane], acc);
        }
    }
    // sum p over the 8 e-lanes within each head group; lane c sits in group c>>3
    ssum += __shfl_xor(ssum, 1, 64);
    ssum += __shfl_xor(ssum, 2, 64);
    ssum += __shfl_xor(ssum, 4, 64);
    float o = acc / (ssum + 1e-16f) + b1[lane];
    out1r[(size_t)n * F1 + lane] = fmaxf(o, 0.f);   // fused +b1, relu
}

// ---------------- layer 2 GEMM: h2 = out1r @ W2 + logits ----------------
// 128 nodes/block, 256 threads, 4x5 register tile, K=64 single step.
__global__ __launch_bounds__(256) void linear2(const float* __restrict__ out1r,
                                               const float* __restrict__ W2,
                                               const float* __restrict__ a_src2,
                                               const float* __restrict__ a_dst2,
                                               float* __restrict__ h2,
                                               float* __restrict__ as2,
                                               float* __restrict__ ad2) {
    __shared__ float xs[128][65];
    __shared__ float ws[64 * 40];
    int t = threadIdx.x;
    int nb = blockIdx.x * 128;
    int colq = t & 15, rr = t >> 4;
#pragma unroll
    for (int i = 0; i < 8; ++i) {
        int r = rr + 16 * i;
        int g = min(nb + r, NN - 1);
        float4 v = *(const float4*)&out1r[(size_t)g * F1 + colq * 4];
        xs[r][colq * 4 + 0] = v.x; xs[r][colq * 4 + 1] = v.y;
        xs[r][colq * 4 + 2] = v.z; xs[r][colq * 4 + 3] = v.w;
    }
#pragma unroll
    for (int i = 0; i < 10; ++i) {
        int idx = t + 256 * i;
        ws[idx] = W2[idx];
    }
    __syncthreads();
    int ct = t & 7, nt = t >> 3;     // c0 = ct*5, n0 = nt*4
    float acc[4][5] = {};
#pragma unroll 4
    for (int k = 0; k < F1; ++k) {
        float w0 = ws[k * 40 + ct * 5 + 0];
        float w1 = ws[k * 40 + ct * 5 + 1];
        float w2 = ws[k * 40 + ct * 5 + 2];
        float w3 = ws[k * 40 + ct * 5 + 3];
        float w4 = ws[k * 40 + ct * 5 + 4];
#pragma unroll
        for (int i = 0; i < 4; ++i) {
            float xv = xs[nt * 4 + i][k];
            acc[i][0] = fmaf(xv, w0, acc[i][0]);
            acc[i][1] = fmaf(xv, w1, acc[i][1]);
            acc[i][2] = fmaf(xv, w2, acc[i][2]);
            acc[i][3] = fmaf(xv, w3, acc[i][3]);
            acc[i][4] = fmaf(xv, w4, acc[i][4]);
        }
    }
    float aw[5], dw[5];
#pragma unroll
    for (int j = 0; j < 5; ++j) { aw[j] = a_src2[ct * 5 + j]; dw[j] = a_dst2[ct * 5 + j]; }
#pragma unroll
    for (int i = 0; i < 4; ++i) {
        int n = nb + nt * 4 + i;
        float vs = acc[i][0] * aw[0] + acc[i][1] * aw[1] + acc[i][2] * aw[2]
                 + acc[i][3] * aw[3] + acc[i][4] * aw[4];
        float vd = acc[i][0] * dw[0] + acc[i][1] * dw[1] + acc[i][2] * dw[2]
                 + acc[i][3] * dw[3] + acc[i][4] * dw[4];
        vs += __shfl_xor(vs, 1, 64); vs += __shfl_xor(vs, 2, 64); vs += __shfl_xor(vs, 4, 64);
        vd += __shfl_xor(vd, 1, 64); vd += __shfl_xor(vd, 2, 64); vd += __shfl_xor(vd, 4, 64);
        if (n < NN) {
#pragma unroll
            for (int j = 0; j < 5; ++j) h2[(size_t)n * F2 + ct * 5 + j] = acc[i][j];
            if (ct == 0) { as2[n] = vs; ad2[n] = vd; }
        }
    }
}

// ---------------- layer 2 softmax+aggregate (+b2) ----------------
// 1 wave/node; p-phase over 64-edge chunks, serial accumulate on lanes<40.
__global__ void node_agg2(const int* __restrict__ row_start, const int* __restrict__ csr_src,
                          const float* __restrict__ as2, const float* __restrict__ ad2,
                          const float* __restrict__ h2, const float* __restrict__ b2,
                          float* __restrict__ out) {
    int n = blockIdx.x;
    int lane = threadIdx.x;
    float adv = ad2[n];
    int lo = row_start[n], hi = row_start[n + 1];
    float ssum = 0.f, acc = 0.f;
    for (int base = lo; base < hi; base += 64) {
        int idx = base + lane;
        bool valid = idx < hi;
        int s = csr_src[valid ? idx : (hi - 1)];
        float v = lrelu(as2[s] + adv);
        float p = valid ? __expf(v) : 0.f;
        ssum += p;
        int cnt = min(hi - base, 64);
        for (int e = 0; e < cnt; ++e) {
            int   sb = __shfl(s, e, 64);
            float pb = __shfl(p, e, 64);
            if (lane < F2) acc = fmaf(pb, h2[(size_t)sb * F2 + lane], acc);
        }
    }
#pragma unroll
    for (int m = 1; m < 64; m <<= 1) ssum += __shfl_xor(ssum, m, 64);
    if (lane < F2) out[(size_t)n * F2 + lane] = acc / (ssum + 1e-16f) + b2[lane];
}

extern "C" void kernel_launch(void* const* d_in, const int* in_sizes, int n_in,
                              void* d_out, int out_size, void* d_ws, size_t ws_size,
                              hipStream_t stream) {
    const float* x      = (const float*)d_in[0];
    const int*   ei     = (const int*)d_in[1];
    const float* W1     = (const float*)d_in[2];
    const float* a_src1 = (const float*)d_in[3];
    const float* a_dst1 = (const float*)d_in[4];
    const float* b1     = (const float*)d_in[5];
    const float* W2     = (const float*)d_in[6];
    const float* a_src2 = (const float*)d_in[7];
    const float* a_dst2 = (const float*)d_in[8];
    const float* b2     = (const float*)d_in[9];
    float* out = (float*)d_out;
    const int* srcp = ei;            // edge_index[0]
    const int* dstp = ei + E_BASE;   // edge_index[1]

    float* ws = (float*)d_ws;
    float* h1        = ws;                                   // N*64
    float* as1       = h1 + (size_t)NN * F1;                 // N*8
    float* ad1       = as1 + (size_t)NN * H1n;               // N*8
    float* out1r     = ad1 + (size_t)NN * H1n;               // N*64
    float* h2        = out1r + (size_t)NN * F1;              // N*40
    float* as2       = h2 + (size_t)NN * F2;                 // N
    float* ad2       = as2 + NN;                             // N
    int*   row_start = (int*)(ad2 + NN);                     // N+1
    int*   csr_src   = row_start + (NN + 1);                 // E_TOT
    int*   deg       = (int*)h1;                             // N (aliased; CSR done pre-linear1)
    int*   cursor    = deg + NN;                             // N (aliased)

    hipMemsetAsync(deg, 0, 2 * (size_t)NN * sizeof(int), stream);

    int eb = (E_TOT + 255) / 256;
    count_deg<<<eb, 256, 0, stream>>>(dstp, deg);
    scan_deg<<<1, 1024, 0, stream>>>(deg, row_start);
    scatter_csr<<<eb, 256, 0, stream>>>(srcp, dstp, row_start, cursor, csr_src);

    linear1<<<(NN + 63) / 64, 256, 0, stream>>>(x, W1, h1);
    logits1<<<(NN * H1n + 255) / 256, 256, 0, stream>>>(h1, a_src1, a_dst1, as1, ad1);
    node_agg1<<<NN, 64, 0, stream>>>(row_start, csr_src, as1, ad1, h1, b1, out1r);

    linear2<<<(NN + 127) / 128, 256, 0, stream>>>(out1r, W2, a_src2, a_dst2, h2, as2, ad2);
    node_agg2<<<NN, 64, 0, stream>>>(row_start, csr_src, as2, ad2, h2, b2, out);
}

// Round 4
// 461.175 us; speedup vs baseline: 4.9004x; 1.2885x over previous
//
#include <hip/hip_runtime.h>
#include <math.h>

constexpr int NN     = 100000;
constexpr int E_BASE = 1600000;
constexpr int E_TOT  = E_BASE + NN;   // self-loops appended
constexpr int F_IN   = 128;
constexpr int F1     = 64;            // H1*C1
constexpr int H1n    = 8;
constexpr int F2     = 40;            // layer-2 out (H=1)

// hierarchical scan geometry: 16 deg-entries per thread
constexpr int SC_PER  = 16;
constexpr int SC_THR  = (NN + SC_PER - 1) / SC_PER;   // 6250
constexpr int SC_BLKS = (SC_THR + 255) / 256;         // 25
constexpr int SC_PAD  = SC_BLKS * 256;                // 6400

__device__ __forceinline__ float lrelu(float v) { return fmaxf(v, 0.2f * v); }

// ---------------- CSR build (by dst) ----------------
__global__ void count_deg(const int* __restrict__ dst, int* __restrict__ deg) {
    int e = blockIdx.x * blockDim.x + threadIdx.x;
    if (e >= E_TOT) return;
    int d = (e < E_BASE) ? dst[e] : (e - E_BASE);
    atomicAdd(&deg[d], 1);
}

// phase A: per-thread partial sums of 16 contiguous deg entries
__global__ void scanA(const int* __restrict__ deg, int* __restrict__ tsum) {
    int g = blockIdx.x * 256 + threadIdx.x;
    int s = 0;
    if (g < SC_THR) {
        int base = g * SC_PER;
#pragma unroll
        for (int i = 0; i < SC_PER; ++i) s += deg[base + i];
    }
    tsum[g] = s;
}

// phase B: exclusive scan of the 6400 partials (single block)
__global__ void scanB(int* __restrict__ tsum, int* __restrict__ row_start) {
    __shared__ int sh[SC_PAD];
    __shared__ int part[1024];
    int t = threadIdx.x;
    for (int i = t; i < SC_PAD; i += 1024) sh[i] = tsum[i];
    __syncthreads();
    const int CH = (SC_PAD + 1023) / 1024;             // 7
    int lo = min(t * CH, SC_PAD), hi = min(lo + CH, SC_PAD);
    int s = 0;
    for (int i = lo; i < hi; ++i) s += sh[i];
    part[t] = s;
    __syncthreads();
    for (int off = 1; off < 1024; off <<= 1) {
        int v = (t >= off) ? part[t - off] : 0;
        __syncthreads();
        part[t] += v;
        __syncthreads();
    }
    int base = (t == 0) ? 0 : part[t - 1];
    for (int i = lo; i < hi; ++i) { int v = sh[i]; tsum[i] = base; base += v; }
    if (t == 1023) row_start[NN] = part[1023];
}

// phase C: expand per-thread chunk offsets to row_start
__global__ void scanC(const int* __restrict__ deg, const int* __restrict__ tsum,
                      int* __restrict__ row_start) {
    int g = blockIdx.x * 256 + threadIdx.x;
    if (g >= SC_THR) return;
    int base = tsum[g];
    int idx = g * SC_PER;
#pragma unroll
    for (int i = 0; i < SC_PER; ++i) {
        int v = deg[idx + i];
        row_start[idx + i] = base;
        base += v;
    }
}

__global__ void scatter_csr(const int* __restrict__ src, const int* __restrict__ dst,
                            const int* __restrict__ row_start, int* __restrict__ cursor,
                            int* __restrict__ csr_src) {
    int e = blockIdx.x * blockDim.x + threadIdx.x;
    if (e >= E_TOT) return;
    int s, d;
    if (e < E_BASE) { s = src[e]; d = dst[e]; }
    else            { s = e - E_BASE; d = s; }
    int pos = atomicAdd(&cursor[d], 1);
    csr_src[row_start[d] + pos] = s;
}

// ---------------- layer 1 GEMM: h1 = x @ W1 (tiled) ----------------
__global__ __launch_bounds__(256) void linear1(const float* __restrict__ x,
                                               const float* __restrict__ W1,
                                               float* __restrict__ h1) {
    __shared__ float xs[64][36];
    __shared__ float ws[32 * 64];
    int t = threadIdx.x;
    int nb = blockIdx.x * 64;
    int ct = t & 15, nt = t >> 4;
    int rs = t >> 3, qs = t & 7;
    float acc[4][4] = {};
    for (int K0 = 0; K0 < F_IN; K0 += 32) {
        int r0 = min(nb + rs, NN - 1);
        int r1 = min(nb + rs + 32, NN - 1);
        float4 v0 = *(const float4*)&x[(size_t)r0 * F_IN + K0 + qs * 4];
        float4 v1 = *(const float4*)&x[(size_t)r1 * F_IN + K0 + qs * 4];
        *(float4*)&xs[rs][qs * 4] = v0;
        *(float4*)&xs[rs + 32][qs * 4] = v1;
        const float4* wsrc = (const float4*)&W1[(size_t)K0 * F1];
        *(float4*)&ws[t * 4] = wsrc[t];
        *(float4*)&ws[1024 + t * 4] = wsrc[256 + t];
        __syncthreads();
#pragma unroll 8
        for (int kk = 0; kk < 32; ++kk) {
            float4 w = *(const float4*)&ws[kk * 64 + ct * 4];
            float x0 = xs[nt * 4 + 0][kk];
            float x1 = xs[nt * 4 + 1][kk];
            float x2 = xs[nt * 4 + 2][kk];
            float x3 = xs[nt * 4 + 3][kk];
            acc[0][0] = fmaf(x0, w.x, acc[0][0]); acc[0][1] = fmaf(x0, w.y, acc[0][1]);
            acc[0][2] = fmaf(x0, w.z, acc[0][2]); acc[0][3] = fmaf(x0, w.w, acc[0][3]);
            acc[1][0] = fmaf(x1, w.x, acc[1][0]); acc[1][1] = fmaf(x1, w.y, acc[1][1]);
            acc[1][2] = fmaf(x1, w.z, acc[1][2]); acc[1][3] = fmaf(x1, w.w, acc[1][3]);
            acc[2][0] = fmaf(x2, w.x, acc[2][0]); acc[2][1] = fmaf(x2, w.y, acc[2][1]);
            acc[2][2] = fmaf(x2, w.z, acc[2][2]); acc[2][3] = fmaf(x2, w.w, acc[2][3]);
            acc[3][0] = fmaf(x3, w.x, acc[3][0]); acc[3][1] = fmaf(x3, w.y, acc[3][1]);
            acc[3][2] = fmaf(x3, w.z, acc[3][2]); acc[3][3] = fmaf(x3, w.w, acc[3][3]);
        }
        __syncthreads();
    }
#pragma unroll
    for (int i = 0; i < 4; ++i) {
        int n = nb + nt * 4 + i;
        if (n < NN) {
            float4 o = make_float4(acc[i][0], acc[i][1], acc[i][2], acc[i][3]);
            *(float4*)&h1[(size_t)n * F1 + ct * 4] = o;
        }
    }
}

// ---------------- layer 1 logits ----------------
__global__ void logits1(const float* __restrict__ h1, const float* __restrict__ a_src,
                        const float* __restrict__ a_dst, float* __restrict__ as1,
                        float* __restrict__ ad1) {
    int t = blockIdx.x * 256 + threadIdx.x;     // t = n*8 + h
    if (t >= NN * H1n) return;
    int h = t & 7;
    const float4* hp = (const float4*)&h1[(size_t)t * 8];
    float4 u0 = hp[0], u1 = hp[1];
    const float4* ap = (const float4*)&a_src[h * 8];
    const float4* dp = (const float4*)&a_dst[h * 8];
    float4 a0 = ap[0], a1 = ap[1], d0 = dp[0], d1 = dp[1];
    float vs = u0.x * a0.x + u0.y * a0.y + u0.z * a0.z + u0.w * a0.w
             + u1.x * a1.x + u1.y * a1.y + u1.z * a1.z + u1.w * a1.w;
    float vd = u0.x * d0.x + u0.y * d0.y + u0.z * d0.z + u0.w * d0.w
             + u1.x * d1.x + u1.y * d1.y + u1.z * d1.z + u1.w * d1.w;
    as1[t] = vs;
    ad1[t] = vd;
}

// ---------------- layer 1 softmax+aggregate ----------------
__global__ void node_agg1(const int* __restrict__ row_start, const int* __restrict__ csr_src,
                          const float* __restrict__ as1, const float* __restrict__ ad1,
                          const float* __restrict__ h1, const float* __restrict__ b1,
                          float* __restrict__ out1r) {
    int n = blockIdx.x;
    int lane = threadIdx.x;          // channel c; head = lane>>3 (both phases)
    float adv = ad1[n * H1n + (lane >> 3)];
    int lo = row_start[n], hi = row_start[n + 1];
    float ssum = 0.f, acc = 0.f;
    for (int base = lo; base < hi; base += 8) {
        int idx = base + (lane & 7);
        bool valid = idx < hi;
        int s = csr_src[valid ? idx : (hi - 1)];
        float v = lrelu(as1[s * H1n + (lane >> 3)] + adv);
        float p = valid ? __expf(v) : 0.f;
        ssum += p;
        int cnt = min(hi - base, 8);
        for (int e = 0; e < cnt; ++e) {
            int   sb = __shfl(s, e, 64);
            float pb = __shfl(p, (lane & 56) | e, 64);
            acc = fmaf(pb, h1[(size_t)sb * F1 + lane], acc);
        }
    }
    ssum += __shfl_xor(ssum, 1, 64);
    ssum += __shfl_xor(ssum, 2, 64);
    ssum += __shfl_xor(ssum, 4, 64);
    float o = acc / (ssum + 1e-16f) + b1[lane];
    out1r[(size_t)n * F1 + lane] = fmaxf(o, 0.f);   // fused +b1, relu
}

// ---------------- layer 2 GEMM: h2 = out1r @ W2 + logits ----------------
__global__ __launch_bounds__(256) void linear2(const float* __restrict__ out1r,
                                               const float* __restrict__ W2,
                                               const float* __restrict__ a_src2,
                                               const float* __restrict__ a_dst2,
                                               float* __restrict__ h2,
                                               float* __restrict__ as2,
                                               float* __restrict__ ad2) {
    __shared__ float xs[128][65];
    __shared__ float ws[64 * 40];
    int t = threadIdx.x;
    int nb = blockIdx.x * 128;
    int colq = t & 15, rr = t >> 4;
#pragma unroll
    for (int i = 0; i < 8; ++i) {
        int r = rr + 16 * i;
        int g = min(nb + r, NN - 1);
        float4 v = *(const float4*)&out1r[(size_t)g * F1 + colq * 4];
        xs[r][colq * 4 + 0] = v.x; xs[r][colq * 4 + 1] = v.y;
        xs[r][colq * 4 + 2] = v.z; xs[r][colq * 4 + 3] = v.w;
    }
#pragma unroll
    for (int i = 0; i < 10; ++i) {
        int idx = t + 256 * i;
        ws[idx] = W2[idx];
    }
    __syncthreads();
    int ct = t & 7, nt = t >> 3;
    float acc[4][5] = {};
#pragma unroll 4
    for (int k = 0; k < F1; ++k) {
        float w0 = ws[k * 40 + ct * 5 + 0];
        float w1 = ws[k * 40 + ct * 5 + 1];
        float w2 = ws[k * 40 + ct * 5 + 2];
        float w3 = ws[k * 40 + ct * 5 + 3];
        float w4 = ws[k * 40 + ct * 5 + 4];
#pragma unroll
        for (int i = 0; i < 4; ++i) {
            float xv = xs[nt * 4 + i][k];
            acc[i][0] = fmaf(xv, w0, acc[i][0]);
            acc[i][1] = fmaf(xv, w1, acc[i][1]);
            acc[i][2] = fmaf(xv, w2, acc[i][2]);
            acc[i][3] = fmaf(xv, w3, acc[i][3]);
            acc[i][4] = fmaf(xv, w4, acc[i][4]);
        }
    }
    float aw[5], dw[5];
#pragma unroll
    for (int j = 0; j < 5; ++j) { aw[j] = a_src2[ct * 5 + j]; dw[j] = a_dst2[ct * 5 + j]; }
#pragma unroll
    for (int i = 0; i < 4; ++i) {
        int n = nb + nt * 4 + i;
        float vs = acc[i][0] * aw[0] + acc[i][1] * aw[1] + acc[i][2] * aw[2]
                 + acc[i][3] * aw[3] + acc[i][4] * aw[4];
        float vd = acc[i][0] * dw[0] + acc[i][1] * dw[1] + acc[i][2] * dw[2]
                 + acc[i][3] * dw[3] + acc[i][4] * dw[4];
        vs += __shfl_xor(vs, 1, 64); vs += __shfl_xor(vs, 2, 64); vs += __shfl_xor(vs, 4, 64);
        vd += __shfl_xor(vd, 1, 64); vd += __shfl_xor(vd, 2, 64); vd += __shfl_xor(vd, 4, 64);
        if (n < NN) {
#pragma unroll
            for (int j = 0; j < 5; ++j) h2[(size_t)n * F2 + ct * 5 + j] = acc[i][j];
            if (ct == 0) { as2[n] = vs; ad2[n] = vd; }
        }
    }
}

// ---------------- layer 2 softmax+aggregate (+b2) ----------------
__global__ void node_agg2(const int* __restrict__ row_start, const int* __restrict__ csr_src,
                          const float* __restrict__ as2, const float* __restrict__ ad2,
                          const float* __restrict__ h2, const float* __restrict__ b2,
                          float* __restrict__ out) {
    int n = blockIdx.x;
    int lane = threadIdx.x;
    float adv = ad2[n];
    int lo = row_start[n], hi = row_start[n + 1];
    float ssum = 0.f, acc = 0.f;
    for (int base = lo; base < hi; base += 64) {
        int idx = base + lane;
        bool valid = idx < hi;
        int s = csr_src[valid ? idx : (hi - 1)];
        float v = lrelu(as2[s] + adv);
        float p = valid ? __expf(v) : 0.f;
        ssum += p;
        int cnt = min(hi - base, 64);
        for (int e = 0; e < cnt; ++e) {
            int   sb = __shfl(s, e, 64);
            float pb = __shfl(p, e, 64);
            if (lane < F2) acc = fmaf(pb, h2[(size_t)sb * F2 + lane], acc);
        }
    }
#pragma unroll
    for (int m = 1; m < 64; m <<= 1) ssum += __shfl_xor(ssum, m, 64);
    if (lane < F2) out[(size_t)n * F2 + lane] = acc / (ssum + 1e-16f) + b2[lane];
}

extern "C" void kernel_launch(void* const* d_in, const int* in_sizes, int n_in,
                              void* d_out, int out_size, void* d_ws, size_t ws_size,
                              hipStream_t stream) {
    const float* x      = (const float*)d_in[0];
    const int*   ei     = (const int*)d_in[1];
    const float* W1     = (const float*)d_in[2];
    const float* a_src1 = (const float*)d_in[3];
    const float* a_dst1 = (const float*)d_in[4];
    const float* b1     = (const float*)d_in[5];
    const float* W2     = (const float*)d_in[6];
    const float* a_src2 = (const float*)d_in[7];
    const float* a_dst2 = (const float*)d_in[8];
    const float* b2     = (const float*)d_in[9];
    float* out = (float*)d_out;
    const int* srcp = ei;            // edge_index[0]
    const int* dstp = ei + E_BASE;   // edge_index[1]

    float* ws = (float*)d_ws;
    float* h1        = ws;                                   // N*64
    float* as1       = h1 + (size_t)NN * F1;                 // N*8
    float* ad1       = as1 + (size_t)NN * H1n;               // N*8
    float* out1r     = ad1 + (size_t)NN * H1n;               // N*64
    float* h2        = out1r + (size_t)NN * F1;              // N*40
    float* as2       = h2 + (size_t)NN * F2;                 // N
    float* ad2       = as2 + NN;                             // N
    int*   row_start = (int*)(ad2 + NN);                     // N+1
    int*   csr_src   = row_start + (NN + 1);                 // E_TOT
    int*   tsum      = csr_src + E_TOT;                      // SC_PAD
    int*   deg       = (int*)h1;                             // N (aliased; CSR done pre-linear1)
    int*   cursor    = deg + NN;                             // N (aliased)

    hipMemsetAsync(deg, 0, 2 * (size_t)NN * sizeof(int), stream);

    int eb = (E_TOT + 255) / 256;
    count_deg<<<eb, 256, 0, stream>>>(dstp, deg);
    scanA<<<SC_BLKS, 256, 0, stream>>>(deg, tsum);
    scanB<<<1, 1024, 0, stream>>>(tsum, row_start);
    scanC<<<SC_BLKS, 256, 0, stream>>>(deg, tsum, row_start);
    scatter_csr<<<eb, 256, 0, stream>>>(srcp, dstp, row_start, cursor, csr_src);

    linear1<<<(NN + 63) / 64, 256, 0, stream>>>(x, W1, h1);
    logits1<<<(NN * H1n + 255) / 256, 256, 0, stream>>>(h1, a_src1, a_dst1, as1, ad1);
    node_agg1<<<NN, 64, 0, stream>>>(row_start, csr_src, as1, ad1, h1, b1, out1r);

    linear2<<<(NN + 127) / 128, 256, 0, stream>>>(out1r, W2, a_src2, a_dst2, h2, as2, ad2);
    node_agg2<<<NN, 64, 0, stream>>>(row_start, csr_src, as2, ad2, h2, b2, out);
}

// Round 5
// 263.332 us; speedup vs baseline: 8.5820x; 1.7513x over previous
//
#include <hip/hip_runtime.h>
#include <math.h>

constexpr int NN     = 100000;
constexpr int E_BASE = 1600000;
constexpr int E_TOT  = E_BASE + NN;   // self-loops appended
constexpr int F_IN   = 128;
constexpr int F1     = 64;            // H1*C1
constexpr int H1n    = 8;
constexpr int F2     = 40;            // layer-2 out (H=1)

// hierarchical scan geometry: 16 deg-entries per thread
constexpr int SC_PER  = 16;
constexpr int SC_THR  = (NN + SC_PER - 1) / SC_PER;   // 6250
constexpr int SC_BLKS = (SC_THR + 255) / 256;         // 25
constexpr int SC_PAD  = SC_BLKS * 256;                // 6400

__device__ __forceinline__ float lrelu(float v) { return fmaxf(v, 0.2f * v); }

// pack two f32 into bf16x2 (low 16 bits = first arg), round-half-up
__device__ __forceinline__ unsigned bpack(float a, float b) {
    unsigned ua = __float_as_uint(a) + 0x8000u;
    unsigned ub = __float_as_uint(b) + 0x8000u;
    return (ua >> 16) | (ub & 0xFFFF0000u);
}
__device__ __forceinline__ float blo(unsigned u) { return __uint_as_float(u << 16); }
__device__ __forceinline__ float bhi(unsigned u) { return __uint_as_float(u & 0xFFFF0000u); }

// ---------------- CSR build (by dst) ----------------
__global__ void count_deg_pos(const int* __restrict__ dst, int* __restrict__ deg,
                              int* __restrict__ pos) {
    int e = blockIdx.x * blockDim.x + threadIdx.x;
    if (e >= E_TOT) return;
    int d = (e < E_BASE) ? dst[e] : (e - E_BASE);
    pos[e] = atomicAdd(&deg[d], 1);
}

__global__ void scanA(const int* __restrict__ deg, int* __restrict__ tsum) {
    int g = blockIdx.x * 256 + threadIdx.x;
    int s = 0;
    if (g < SC_THR) {
        int base = g * SC_PER;
#pragma unroll
        for (int i = 0; i < SC_PER; ++i) s += deg[base + i];
    }
    tsum[g] = s;
}

__global__ void scanB(int* __restrict__ tsum, int* __restrict__ row_start) {
    __shared__ int sh[SC_PAD];
    __shared__ int part[1024];
    int t = threadIdx.x;
    for (int i = t; i < SC_PAD; i += 1024) sh[i] = tsum[i];
    __syncthreads();
    const int CH = (SC_PAD + 1023) / 1024;             // 7
    int lo = min(t * CH, SC_PAD), hi = min(lo + CH, SC_PAD);
    int s = 0;
    for (int i = lo; i < hi; ++i) s += sh[i];
    part[t] = s;
    __syncthreads();
    for (int off = 1; off < 1024; off <<= 1) {
        int v = (t >= off) ? part[t - off] : 0;
        __syncthreads();
        part[t] += v;
        __syncthreads();
    }
    int base = (t == 0) ? 0 : part[t - 1];
    for (int i = lo; i < hi; ++i) { int v = sh[i]; tsum[i] = base; base += v; }
    if (t == 1023) row_start[NN] = part[1023];
}

__global__ void scanC(const int* __restrict__ deg, const int* __restrict__ tsum,
                      int* __restrict__ row_start) {
    int g = blockIdx.x * 256 + threadIdx.x;
    if (g >= SC_THR) return;
    int base = tsum[g];
    int idx = g * SC_PER;
#pragma unroll
    for (int i = 0; i < SC_PER; ++i) {
        int v = deg[idx + i];
        row_start[idx + i] = base;
        base += v;
    }
}

// atomic-free scatter using captured positions
__global__ void scatter_csr2(const int* __restrict__ src, const int* __restrict__ dst,
                             const int* __restrict__ row_start, const int* __restrict__ pos,
                             int* __restrict__ csr_src) {
    int e = blockIdx.x * blockDim.x + threadIdx.x;
    if (e >= E_TOT) return;
    int s, d;
    if (e < E_BASE) { s = src[e]; d = dst[e]; }
    else            { s = e - E_BASE; d = s; }
    csr_src[row_start[d] + pos[e]] = s;
}

// ---------------- layer 1 GEMM: h1b(bf16) = x @ W1, fused logits ----------
__global__ __launch_bounds__(256) void linear1(const float* __restrict__ x,
                                               const float* __restrict__ W1,
                                               const float* __restrict__ a_src,
                                               const float* __restrict__ a_dst,
                                               unsigned* __restrict__ h1b,
                                               float* __restrict__ as1,
                                               float* __restrict__ ad1) {
    __shared__ float xs[64][36];
    __shared__ float ws[32 * 64];
    int t = threadIdx.x;
    int nb = blockIdx.x * 64;
    int ct = t & 15, nt = t >> 4;
    int rs = t >> 3, qs = t & 7;
    float acc[4][4] = {};
    for (int K0 = 0; K0 < F_IN; K0 += 32) {
        int r0 = min(nb + rs, NN - 1);
        int r1 = min(nb + rs + 32, NN - 1);
        float4 v0 = *(const float4*)&x[(size_t)r0 * F_IN + K0 + qs * 4];
        float4 v1 = *(const float4*)&x[(size_t)r1 * F_IN + K0 + qs * 4];
        *(float4*)&xs[rs][qs * 4] = v0;
        *(float4*)&xs[rs + 32][qs * 4] = v1;
        const float4* wsrc = (const float4*)&W1[(size_t)K0 * F1];
        *(float4*)&ws[t * 4] = wsrc[t];
        *(float4*)&ws[1024 + t * 4] = wsrc[256 + t];
        __syncthreads();
#pragma unroll 8
        for (int kk = 0; kk < 32; ++kk) {
            float4 w = *(const float4*)&ws[kk * 64 + ct * 4];
            float x0 = xs[nt * 4 + 0][kk];
            float x1 = xs[nt * 4 + 1][kk];
            float x2 = xs[nt * 4 + 2][kk];
            float x3 = xs[nt * 4 + 3][kk];
            acc[0][0] = fmaf(x0, w.x, acc[0][0]); acc[0][1] = fmaf(x0, w.y, acc[0][1]);
            acc[0][2] = fmaf(x0, w.z, acc[0][2]); acc[0][3] = fmaf(x0, w.w, acc[0][3]);
            acc[1][0] = fmaf(x1, w.x, acc[1][0]); acc[1][1] = fmaf(x1, w.y, acc[1][1]);
            acc[1][2] = fmaf(x1, w.z, acc[1][2]); acc[1][3] = fmaf(x1, w.w, acc[1][3]);
            acc[2][0] = fmaf(x2, w.x, acc[2][0]); acc[2][1] = fmaf(x2, w.y, acc[2][1]);
            acc[2][2] = fmaf(x2, w.z, acc[2][2]); acc[2][3] = fmaf(x2, w.w, acc[2][3]);
            acc[3][0] = fmaf(x3, w.x, acc[3][0]); acc[3][1] = fmaf(x3, w.y, acc[3][1]);
            acc[3][2] = fmaf(x3, w.z, acc[3][2]); acc[3][3] = fmaf(x3, w.w, acc[3][3]);
        }
        __syncthreads();
    }
    float4 as4 = ((const float4*)a_src)[ct];
    float4 ds4 = ((const float4*)a_dst)[ct];
#pragma unroll
    for (int i = 0; i < 4; ++i) {
        int n = nb + nt * 4 + i;
        // bf16 pack: channels ct*4..ct*4+3 -> uints ct*2, ct*2+1
        unsigned u0 = bpack(acc[i][0], acc[i][1]);
        unsigned u1 = bpack(acc[i][2], acc[i][3]);
        // per-head logits: head = ct>>1 spans ct pairs
        float ps = acc[i][0] * as4.x + acc[i][1] * as4.y + acc[i][2] * as4.z + acc[i][3] * as4.w;
        float pd = acc[i][0] * ds4.x + acc[i][1] * ds4.y + acc[i][2] * ds4.z + acc[i][3] * ds4.w;
        ps += __shfl_xor(ps, 1, 64);
        pd += __shfl_xor(pd, 1, 64);
        if (n < NN) {
            *(uint2*)&h1b[(size_t)n * 32 + ct * 2] = make_uint2(u0, u1);
            if (!(ct & 1)) {
                as1[n * H1n + (ct >> 1)] = ps;
                ad1[n * H1n + (ct >> 1)] = pd;
            }
        }
    }
}

// ---------------- layer 1 softmax+aggregate (bf16 gather, pair-streamed) --
// p-phase: lane=(head<<3)|e over 8-edge chunks.
// acc-phase: stream q=lane>>5 handles edges 2j+q; lane owns channels 2il,2il+1.
__global__ void node_agg1(const int* __restrict__ row_start, const int* __restrict__ csr_src,
                          const float* __restrict__ as1, const float* __restrict__ ad1,
                          const unsigned* __restrict__ h1b, const float* __restrict__ b1,
                          float* __restrict__ out1r) {
    int n = blockIdx.x;
    int lane = threadIdx.x;
    int e8 = lane & 7, hp = lane >> 3;        // p-phase coords
    int il = lane & 31, q = lane >> 5;        // acc coords
    int hc = il >> 2;                         // head of channel pair (2il)>>3
    float adv = ad1[n * H1n + hp];
    int lo = row_start[n], hi = row_start[n + 1];
    float ssum = 0.f, acc0 = 0.f, acc1 = 0.f;
    for (int base = lo; base < hi; base += 8) {
        int idx = base + e8;
        bool valid = idx < hi;
        int s = csr_src[valid ? idx : (hi - 1)];
        float v = lrelu(as1[s * H1n + hp] + adv);
        float p = valid ? __expf(v) : 0.f;
        ssum += p;
#pragma unroll
        for (int j = 0; j < 4; ++j) {
            int e = 2 * j + q;
            int   sb = __shfl(s, e, 64);
            float pb = __shfl(p, (hc << 3) | e, 64);
            unsigned u = h1b[(size_t)sb * 32 + il];
            acc0 = fmaf(pb, blo(u), acc0);
            acc1 = fmaf(pb, bhi(u), acc1);
        }
    }
    // head totals: reduce over e-slots within each 8-lane group
    ssum += __shfl_xor(ssum, 1, 64);
    ssum += __shfl_xor(ssum, 2, 64);
    ssum += __shfl_xor(ssum, 4, 64);
    float sh = __shfl(ssum, hc << 3, 64);     // total for this channel-pair's head
    float p0 = acc0 + __shfl(acc0, il | 32, 64);
    float p1 = acc1 + __shfl(acc1, il | 32, 64);
    if (lane < 32) {
        float r = 1.f / (sh + 1e-16f);
        float2 bv = ((const float2*)b1)[il];
        float2 o;
        o.x = fmaxf(fmaf(p0, r, bv.x), 0.f);
        o.y = fmaxf(fmaf(p1, r, bv.y), 0.f);
        ((float2*)(out1r + (size_t)n * F1))[il] = o;
    }
}

// ---------------- layer 2 GEMM: h2b(bf16) = out1r @ W2, fused logits ------
__global__ __launch_bounds__(256) void linear2(const float* __restrict__ out1r,
                                               const float* __restrict__ W2,
                                               const float* __restrict__ a_src2,
                                               const float* __restrict__ a_dst2,
                                               unsigned* __restrict__ h2b,
                                               float* __restrict__ as2,
                                               float* __restrict__ ad2) {
    __shared__ float xs[128][65];
    __shared__ float ws[64 * 40];
    int t = threadIdx.x;
    int nb = blockIdx.x * 128;
    int colq = t & 15, rr = t >> 4;
#pragma unroll
    for (int i = 0; i < 8; ++i) {
        int r = rr + 16 * i;
        int g = min(nb + r, NN - 1);
        float4 v = *(const float4*)&out1r[(size_t)g * F1 + colq * 4];
        xs[r][colq * 4 + 0] = v.x; xs[r][colq * 4 + 1] = v.y;
        xs[r][colq * 4 + 2] = v.z; xs[r][colq * 4 + 3] = v.w;
    }
#pragma unroll
    for (int i = 0; i < 10; ++i) ws[t + 256 * i] = W2[t + 256 * i];
    __syncthreads();
    int ct = t & 7, nt = t >> 3;
    float acc[4][5] = {};
#pragma unroll 4
    for (int k = 0; k < F1; ++k) {
        float w0 = ws[k * 40 + ct * 5 + 0];
        float w1 = ws[k * 40 + ct * 5 + 1];
        float w2 = ws[k * 40 + ct * 5 + 2];
        float w3 = ws[k * 40 + ct * 5 + 3];
        float w4 = ws[k * 40 + ct * 5 + 4];
#pragma unroll
        for (int i = 0; i < 4; ++i) {
            float xv = xs[nt * 4 + i][k];
            acc[i][0] = fmaf(xv, w0, acc[i][0]);
            acc[i][1] = fmaf(xv, w1, acc[i][1]);
            acc[i][2] = fmaf(xv, w2, acc[i][2]);
            acc[i][3] = fmaf(xv, w3, acc[i][3]);
            acc[i][4] = fmaf(xv, w4, acc[i][4]);
        }
    }
    float aw[5], dw[5];
#pragma unroll
    for (int j = 0; j < 5; ++j) { aw[j] = a_src2[ct * 5 + j]; dw[j] = a_dst2[ct * 5 + j]; }
#pragma unroll
    for (int i = 0; i < 4; ++i) {
        int n = nb + nt * 4 + i;
        float vs = acc[i][0] * aw[0] + acc[i][1] * aw[1] + acc[i][2] * aw[2]
                 + acc[i][3] * aw[3] + acc[i][4] * aw[4];
        float vd = acc[i][0] * dw[0] + acc[i][1] * dw[1] + acc[i][2] * dw[2]
                 + acc[i][3] * dw[3] + acc[i][4] * dw[4];
        vs += __shfl_xor(vs, 1, 64); vs += __shfl_xor(vs, 2, 64); vs += __shfl_xor(vs, 4, 64);
        vd += __shfl_xor(vd, 1, 64); vd += __shfl_xor(vd, 2, 64); vd += __shfl_xor(vd, 4, 64);
        if (n < NN && ct == 0) { as2[n] = vs; ad2[n] = vd; }
    }
    // repack acc -> bf16 h2b via LDS
    __syncthreads();
#pragma unroll
    for (int i = 0; i < 4; ++i) {
        int r = nt * 4 + i;
#pragma unroll
        for (int j = 0; j < 5; ++j) xs[r][ct * 5 + j] = acc[i][j];
    }
    __syncthreads();
    {
        int r = t >> 1, half = t & 1;
        int n = nb + r;
        if (n < NN) {
            unsigned* dp = h2b + (size_t)n * 20 + half * 10;
#pragma unroll
            for (int k = 0; k < 10; ++k)
                dp[k] = bpack(xs[r][half * 20 + 2 * k], xs[r][half * 20 + 2 * k + 1]);
        }
    }
}

// ---------------- layer 2 softmax+aggregate (+b2, bf16 gather) ------------
__global__ void node_agg2(const int* __restrict__ row_start, const int* __restrict__ csr_src,
                          const float* __restrict__ as2, const float* __restrict__ ad2,
                          const unsigned* __restrict__ h2b, const float* __restrict__ b2,
                          float* __restrict__ out) {
    int n = blockIdx.x;
    int lane = threadIdx.x;
    int e8 = lane & 7;
    int il = lane & 31, q = lane >> 5;        // stream q, channels 2il,2il+1 (il<20)
    bool act = il < 20;
    float adv = ad2[n];
    int lo = row_start[n], hi = row_start[n + 1];
    float ssum = 0.f, acc0 = 0.f, acc1 = 0.f;
    for (int base = lo; base < hi; base += 8) {
        int idx = base + e8;
        bool valid = idx < hi;
        int s = csr_src[valid ? idx : (hi - 1)];
        float v = lrelu(as2[s] + adv);
        float p = valid ? __expf(v) : 0.f;
        ssum += p;
#pragma unroll
        for (int j = 0; j < 4; ++j) {
            int e = 2 * j + q;
            int   sb = __shfl(s, e, 64);
            float pb = __shfl(p, e, 64);
            unsigned u = act ? h2b[(size_t)sb * 20 + il] : 0u;
            acc0 = fmaf(pb, blo(u), acc0);
            acc1 = fmaf(pb, bhi(u), acc1);
        }
    }
    ssum += __shfl_xor(ssum, 1, 64);
    ssum += __shfl_xor(ssum, 2, 64);
    ssum += __shfl_xor(ssum, 4, 64);          // all lanes: denominator
    float p0 = acc0 + __shfl(acc0, il | 32, 64);
    float p1 = acc1 + __shfl(acc1, il | 32, 64);
    if (lane < 32 && act) {
        float r = 1.f / (ssum + 1e-16f);
        float2 bv = ((const float2*)b2)[il];
        float2 o;
        o.x = fmaf(p0, r, bv.x);
        o.y = fmaf(p1, r, bv.y);
        ((float2*)(out + (size_t)n * F2))[il] = o;
    }
}

extern "C" void kernel_launch(void* const* d_in, const int* in_sizes, int n_in,
                              void* d_out, int out_size, void* d_ws, size_t ws_size,
                              hipStream_t stream) {
    const float* x      = (const float*)d_in[0];
    const int*   ei     = (const int*)d_in[1];
    const float* W1     = (const float*)d_in[2];
    const float* a_src1 = (const float*)d_in[3];
    const float* a_dst1 = (const float*)d_in[4];
    const float* b1     = (const float*)d_in[5];
    const float* W2     = (const float*)d_in[6];
    const float* a_src2 = (const float*)d_in[7];
    const float* a_dst2 = (const float*)d_in[8];
    const float* b2     = (const float*)d_in[9];
    float* out = (float*)d_out;
    const int* srcp = ei;            // edge_index[0]
    const int* dstp = ei + E_BASE;   // edge_index[1]

    unsigned* h1b      = (unsigned*)d_ws;                    // N*32 uints
    float*    as1      = (float*)(h1b + (size_t)NN * 32);    // N*8
    float*    ad1      = as1 + (size_t)NN * H1n;             // N*8
    float*    out1r    = ad1 + (size_t)NN * H1n;             // N*64
    unsigned* h2b      = (unsigned*)(out1r + (size_t)NN * F1); // N*20 uints
    float*    as2      = (float*)(h2b + (size_t)NN * 20);    // N
    float*    ad2      = as2 + NN;                           // N
    int*      row_start= (int*)(ad2 + NN);                   // N+1
    int*      csr_src  = row_start + (NN + 1);               // E_TOT
    int*      pos      = csr_src + E_TOT;                    // E_TOT
    int*      tsum     = pos + E_TOT;                        // SC_PAD
    int*      deg      = (int*)h1b;                          // N (CSR phase only)

    hipMemsetAsync(deg, 0, (size_t)NN * sizeof(int), stream);

    int eb = (E_TOT + 255) / 256;
    count_deg_pos<<<eb, 256, 0, stream>>>(dstp, deg, pos);
    scanA<<<SC_BLKS, 256, 0, stream>>>(deg, tsum);
    scanB<<<1, 1024, 0, stream>>>(tsum, row_start);
    scanC<<<SC_BLKS, 256, 0, stream>>>(deg, tsum, row_start);
    scatter_csr2<<<eb, 256, 0, stream>>>(srcp, dstp, row_start, pos, csr_src);

    linear1<<<(NN + 63) / 64, 256, 0, stream>>>(x, W1, a_src1, a_dst1, h1b, as1, ad1);
    node_agg1<<<NN, 64, 0, stream>>>(row_start, csr_src, as1, ad1, h1b, b1, out1r);

    linear2<<<(NN + 127) / 128, 256, 0, stream>>>(out1r, W2, a_src2, a_dst2, h2b, as2, ad2);
    node_agg2<<<NN, 64, 0, stream>>>(row_start, csr_src, as2, ad2, h2b, b2, out);
}

// Round 6
// 218.483 us; speedup vs baseline: 10.3437x; 1.2053x over previous
//
#include <hip/hip_runtime.h>
#include <math.h>

constexpr int NN     = 100000;
constexpr int E_BASE = 1600000;
constexpr int E_TOT  = E_BASE + NN;   // self-loops appended
constexpr int F_IN   = 128;
constexpr int F1     = 64;            // H1*C1
constexpr int H1n    = 8;
constexpr int F2     = 40;            // layer-2 out (H=1)

// bucketed CSR build geometry
constexpr int BSHIFT    = 9;                      // 512 nodes per bucket
constexpr int NB        = (NN + 511) >> BSHIFT;   // 196 buckets
constexpr int BCAP      = 12288;                  // >> mean 8704 (+38 sd)
constexpr int P1_BLOCKS = 256;
constexpr int EPB       = (E_TOT + P1_BLOCKS - 1) / P1_BLOCKS;   // 6641

__device__ __forceinline__ float lrelu(float v) { return fmaxf(v, 0.2f * v); }

// pack two f32 into bf16x2 (low 16 bits = first arg), round-half-up
__device__ __forceinline__ unsigned bpack(float a, float b) {
    unsigned ua = __float_as_uint(a) + 0x8000u;
    unsigned ub = __float_as_uint(b) + 0x8000u;
    return (ua >> 16) | (ub & 0xFFFF0000u);
}
__device__ __forceinline__ float blo(unsigned u) { return __uint_as_float(u << 16); }
__device__ __forceinline__ float bhi(unsigned u) { return __uint_as_float(u & 0xFFFF0000u); }

// ---------------- CSR build: bucket partition (LDS histogram) -------------
__global__ __launch_bounds__(256) void partition(const int* __restrict__ src,
                                                 const int* __restrict__ dst,
                                                 int* __restrict__ bucket_cnt,
                                                 uint2* __restrict__ store) {
    __shared__ int bins[NB];
    __shared__ int base[NB];
    int t = threadIdx.x;
    for (int i = t; i < NB; i += 256) bins[i] = 0;
    __syncthreads();
    int e0 = blockIdx.x * EPB;
    int e1 = min(e0 + EPB, E_TOT);
    for (int e = e0 + t; e < e1; e += 256) {
        int d = (e < E_BASE) ? dst[e] : (e - E_BASE);
        atomicAdd(&bins[d >> BSHIFT], 1);
    }
    __syncthreads();
    for (int i = t; i < NB; i += 256) {
        base[i] = atomicAdd(&bucket_cnt[i], bins[i]);   // reserve range
        bins[i] = 0;                                    // reuse as cursor
    }
    __syncthreads();
    for (int e = e0 + t; e < e1; e += 256) {
        int s, d;
        if (e < E_BASE) { s = src[e]; d = dst[e]; }
        else            { s = e - E_BASE; d = s; }
        int b = d >> BSHIFT;
        int p = atomicAdd(&bins[b], 1);
        store[(size_t)b * BCAP + base[b] + p] = make_uint2((unsigned)s, (unsigned)d);
    }
}

// exclusive scan of 196 bucket totals (tiny)
__global__ void bucket_scan(const int* __restrict__ bucket_cnt,
                            int* __restrict__ bucket_base,
                            int* __restrict__ row_start) {
    if (threadIdx.x == 0) {
        int run = 0;
#pragma unroll 4
        for (int b = 0; b < NB; ++b) { bucket_base[b] = run; run += bucket_cnt[b]; }
        bucket_base[NB] = run;          // == E_TOT
        row_start[NN] = run;
    }
}

// per-bucket CSR: LDS count + wave scan + LDS-cursor placement
__global__ __launch_bounds__(256) void bucket_csr(const int* __restrict__ bucket_cnt,
                                                  const int* __restrict__ bucket_base,
                                                  const uint2* __restrict__ store,
                                                  int* __restrict__ row_start,
                                                  int* __restrict__ csr_src) {
    __shared__ int cnt_l[512];
    __shared__ int incl[512];
    __shared__ int cur_l[512];
    int b = blockIdx.x;
    int t = threadIdx.x;
    int cnt = bucket_cnt[b];
    int gbase = bucket_base[b];
    int nlo = b << BSHIFT;
    int nodes = min(512, NN - nlo);
    cnt_l[t] = 0; cnt_l[t + 256] = 0;
    __syncthreads();
    const uint2* sp = store + (size_t)b * BCAP;
    for (int i = t; i < cnt; i += 256)
        atomicAdd(&cnt_l[(int)sp[i].y - nlo], 1);
    __syncthreads();
    if (t < 64) {                     // single-wave inclusive scan over 512
        int run = 0;
        for (int c = 0; c < 512; c += 64) {
            int v = cnt_l[c + t];
#pragma unroll
            for (int off = 1; off < 64; off <<= 1) {
                int u = __shfl_up(v, off, 64);
                if (t >= off) v += u;
            }
            incl[c + t] = run + v;
            run = __shfl(run + v, 63, 64);
        }
    }
    __syncthreads();
    for (int j = t; j < 512; j += 256) {
        int start = gbase + incl[j] - cnt_l[j];
        cur_l[j] = start;             // global csr cursor
        if (j < nodes) row_start[nlo + j] = start;
    }
    __syncthreads();
    for (int i = t; i < cnt; i += 256) {
        uint2 ed = sp[i];
        int p = atomicAdd(&cur_l[(int)ed.y - nlo], 1);
        csr_src[p] = (int)ed.x;
    }
}

// ---------------- layer 1 GEMM: h1b(bf16) = x @ W1, fused logits ----------
__global__ __launch_bounds__(256) void linear1(const float* __restrict__ x,
                                               const float* __restrict__ W1,
                                               const float* __restrict__ a_src,
                                               const float* __restrict__ a_dst,
                                               unsigned* __restrict__ h1b,
                                               float* __restrict__ as1,
                                               float* __restrict__ ad1) {
    __shared__ float xs[64][36];
    __shared__ float ws[32 * 64];
    int t = threadIdx.x;
    int nb = blockIdx.x * 64;
    int ct = t & 15, nt = t >> 4;
    int rs = t >> 3, qs = t & 7;
    float acc[4][4] = {};
    for (int K0 = 0; K0 < F_IN; K0 += 32) {
        int r0 = min(nb + rs, NN - 1);
        int r1 = min(nb + rs + 32, NN - 1);
        float4 v0 = *(const float4*)&x[(size_t)r0 * F_IN + K0 + qs * 4];
        float4 v1 = *(const float4*)&x[(size_t)r1 * F_IN + K0 + qs * 4];
        *(float4*)&xs[rs][qs * 4] = v0;
        *(float4*)&xs[rs + 32][qs * 4] = v1;
        const float4* wsrc = (const float4*)&W1[(size_t)K0 * F1];
        *(float4*)&ws[t * 4] = wsrc[t];
        *(float4*)&ws[1024 + t * 4] = wsrc[256 + t];
        __syncthreads();
#pragma unroll 8
        for (int kk = 0; kk < 32; ++kk) {
            float4 w = *(const float4*)&ws[kk * 64 + ct * 4];
            float x0 = xs[nt * 4 + 0][kk];
            float x1 = xs[nt * 4 + 1][kk];
            float x2 = xs[nt * 4 + 2][kk];
            float x3 = xs[nt * 4 + 3][kk];
            acc[0][0] = fmaf(x0, w.x, acc[0][0]); acc[0][1] = fmaf(x0, w.y, acc[0][1]);
            acc[0][2] = fmaf(x0, w.z, acc[0][2]); acc[0][3] = fmaf(x0, w.w, acc[0][3]);
            acc[1][0] = fmaf(x1, w.x, acc[1][0]); acc[1][1] = fmaf(x1, w.y, acc[1][1]);
            acc[1][2] = fmaf(x1, w.z, acc[1][2]); acc[1][3] = fmaf(x1, w.w, acc[1][3]);
            acc[2][0] = fmaf(x2, w.x, acc[2][0]); acc[2][1] = fmaf(x2, w.y, acc[2][1]);
            acc[2][2] = fmaf(x2, w.z, acc[2][2]); acc[2][3] = fmaf(x2, w.w, acc[2][3]);
            acc[3][0] = fmaf(x3, w.x, acc[3][0]); acc[3][1] = fmaf(x3, w.y, acc[3][1]);
            acc[3][2] = fmaf(x3, w.z, acc[3][2]); acc[3][3] = fmaf(x3, w.w, acc[3][3]);
        }
        __syncthreads();
    }
    float4 as4 = ((const float4*)a_src)[ct];
    float4 ds4 = ((const float4*)a_dst)[ct];
#pragma unroll
    for (int i = 0; i < 4; ++i) {
        int n = nb + nt * 4 + i;
        unsigned u0 = bpack(acc[i][0], acc[i][1]);
        unsigned u1 = bpack(acc[i][2], acc[i][3]);
        float ps = acc[i][0] * as4.x + acc[i][1] * as4.y + acc[i][2] * as4.z + acc[i][3] * as4.w;
        float pd = acc[i][0] * ds4.x + acc[i][1] * ds4.y + acc[i][2] * ds4.z + acc[i][3] * ds4.w;
        ps += __shfl_xor(ps, 1, 64);
        pd += __shfl_xor(pd, 1, 64);
        if (n < NN) {
            *(uint2*)&h1b[(size_t)n * 32 + ct * 2] = make_uint2(u0, u1);
            if (!(ct & 1)) {
                as1[n * H1n + (ct >> 1)] = ps;
                ad1[n * H1n + (ct >> 1)] = pd;
            }
        }
    }
}

// ---------------- layer 1 softmax+aggregate (bf16 gather, pair-streamed) --
__global__ void node_agg1(const int* __restrict__ row_start, const int* __restrict__ csr_src,
                          const float* __restrict__ as1, const float* __restrict__ ad1,
                          const unsigned* __restrict__ h1b, const float* __restrict__ b1,
                          float* __restrict__ out1r) {
    int n = blockIdx.x;
    int lane = threadIdx.x;
    int e8 = lane & 7, hp = lane >> 3;        // p-phase coords
    int il = lane & 31, q = lane >> 5;        // acc coords
    int hc = il >> 2;                         // head of channel pair (2il)>>3
    float adv = ad1[n * H1n + hp];
    int lo = row_start[n], hi = row_start[n + 1];
    float ssum = 0.f, acc0 = 0.f, acc1 = 0.f;
    for (int base = lo; base < hi; base += 8) {
        int idx = base + e8;
        bool valid = idx < hi;
        int s = csr_src[valid ? idx : (hi - 1)];
        float v = lrelu(as1[s * H1n + hp] + adv);
        float p = valid ? __expf(v) : 0.f;
        ssum += p;
#pragma unroll
        for (int j = 0; j < 4; ++j) {
            int e = 2 * j + q;
            int   sb = __shfl(s, e, 64);
            float pb = __shfl(p, (hc << 3) | e, 64);
            unsigned u = h1b[(size_t)sb * 32 + il];
            acc0 = fmaf(pb, blo(u), acc0);
            acc1 = fmaf(pb, bhi(u), acc1);
        }
    }
    ssum += __shfl_xor(ssum, 1, 64);
    ssum += __shfl_xor(ssum, 2, 64);
    ssum += __shfl_xor(ssum, 4, 64);
    float sh = __shfl(ssum, hc << 3, 64);
    float p0 = acc0 + __shfl(acc0, il | 32, 64);
    float p1 = acc1 + __shfl(acc1, il | 32, 64);
    if (lane < 32) {
        float r = 1.f / (sh + 1e-16f);
        float2 bv = ((const float2*)b1)[il];
        float2 o;
        o.x = fmaxf(fmaf(p0, r, bv.x), 0.f);
        o.y = fmaxf(fmaf(p1, r, bv.y), 0.f);
        ((float2*)(out1r + (size_t)n * F1))[il] = o;
    }
}

// ---------------- layer 2 GEMM: h2b(bf16) = out1r @ W2, fused logits ------
__global__ __launch_bounds__(256) void linear2(const float* __restrict__ out1r,
                                               const float* __restrict__ W2,
                                               const float* __restrict__ a_src2,
                                               const float* __restrict__ a_dst2,
                                               unsigned* __restrict__ h2b,
                                               float* __restrict__ as2,
                                               float* __restrict__ ad2) {
    __shared__ float xs[128][65];
    __shared__ float ws[64 * 40];
    int t = threadIdx.x;
    int nb = blockIdx.x * 128;
    int colq = t & 15, rr = t >> 4;
#pragma unroll
    for (int i = 0; i < 8; ++i) {
        int r = rr + 16 * i;
        int g = min(nb + r, NN - 1);
        float4 v = *(const float4*)&out1r[(size_t)g * F1 + colq * 4];
        xs[r][colq * 4 + 0] = v.x; xs[r][colq * 4 + 1] = v.y;
        xs[r][colq * 4 + 2] = v.z; xs[r][colq * 4 + 3] = v.w;
    }
#pragma unroll
    for (int i = 0; i < 10; ++i) ws[t + 256 * i] = W2[t + 256 * i];
    __syncthreads();
    int ct = t & 7, nt = t >> 3;
    float acc[4][5] = {};
#pragma unroll 4
    for (int k = 0; k < F1; ++k) {
        float w0 = ws[k * 40 + ct * 5 + 0];
        float w1 = ws[k * 40 + ct * 5 + 1];
        float w2 = ws[k * 40 + ct * 5 + 2];
        float w3 = ws[k * 40 + ct * 5 + 3];
        float w4 = ws[k * 40 + ct * 5 + 4];
#pragma unroll
        for (int i = 0; i < 4; ++i) {
            float xv = xs[nt * 4 + i][k];
            acc[i][0] = fmaf(xv, w0, acc[i][0]);
            acc[i][1] = fmaf(xv, w1, acc[i][1]);
            acc[i][2] = fmaf(xv, w2, acc[i][2]);
            acc[i][3] = fmaf(xv, w3, acc[i][3]);
            acc[i][4] = fmaf(xv, w4, acc[i][4]);
        }
    }
    float aw[5], dw[5];
#pragma unroll
    for (int j = 0; j < 5; ++j) { aw[j] = a_src2[ct * 5 + j]; dw[j] = a_dst2[ct * 5 + j]; }
#pragma unroll
    for (int i = 0; i < 4; ++i) {
        int n = nb + nt * 4 + i;
        float vs = acc[i][0] * aw[0] + acc[i][1] * aw[1] + acc[i][2] * aw[2]
                 + acc[i][3] * aw[3] + acc[i][4] * aw[4];
        float vd = acc[i][0] * dw[0] + acc[i][1] * dw[1] + acc[i][2] * dw[2]
                 + acc[i][3] * dw[3] + acc[i][4] * dw[4];
        vs += __shfl_xor(vs, 1, 64); vs += __shfl_xor(vs, 2, 64); vs += __shfl_xor(vs, 4, 64);
        vd += __shfl_xor(vd, 1, 64); vd += __shfl_xor(vd, 2, 64); vd += __shfl_xor(vd, 4, 64);
        if (n < NN && ct == 0) { as2[n] = vs; ad2[n] = vd; }
    }
    __syncthreads();
#pragma unroll
    for (int i = 0; i < 4; ++i) {
        int r = nt * 4 + i;
#pragma unroll
        for (int j = 0; j < 5; ++j) xs[r][ct * 5 + j] = acc[i][j];
    }
    __syncthreads();
    {
        int r = t >> 1, half = t & 1;
        int n = nb + r;
        if (n < NN) {
            unsigned* dp = h2b + (size_t)n * 20 + half * 10;
#pragma unroll
            for (int k = 0; k < 10; ++k)
                dp[k] = bpack(xs[r][half * 20 + 2 * k], xs[r][half * 20 + 2 * k + 1]);
        }
    }
}

// ---------------- layer 2 softmax+aggregate (+b2, bf16 gather) ------------
__global__ void node_agg2(const int* __restrict__ row_start, const int* __restrict__ csr_src,
                          const float* __restrict__ as2, const float* __restrict__ ad2,
                          const unsigned* __restrict__ h2b, const float* __restrict__ b2,
                          float* __restrict__ out) {
    int n = blockIdx.x;
    int lane = threadIdx.x;
    int e8 = lane & 7;
    int il = lane & 31, q = lane >> 5;
    bool act = il < 20;
    float adv = ad2[n];
    int lo = row_start[n], hi = row_start[n + 1];
    float ssum = 0.f, acc0 = 0.f, acc1 = 0.f;
    for (int base = lo; base < hi; base += 8) {
        int idx = base + e8;
        bool valid = idx < hi;
        int s = csr_src[valid ? idx : (hi - 1)];
        float v = lrelu(as2[s] + adv);
        float p = valid ? __expf(v) : 0.f;
        ssum += p;
#pragma unroll
        for (int j = 0; j < 4; ++j) {
            int e = 2 * j + q;
            int   sb = __shfl(s, e, 64);
            float pb = __shfl(p, e, 64);
            unsigned u = act ? h2b[(size_t)sb * 20 + il] : 0u;
            acc0 = fmaf(pb, blo(u), acc0);
            acc1 = fmaf(pb, bhi(u), acc1);
        }
    }
    ssum += __shfl_xor(ssum, 1, 64);
    ssum += __shfl_xor(ssum, 2, 64);
    ssum += __shfl_xor(ssum, 4, 64);
    float p0 = acc0 + __shfl(acc0, il | 32, 64);
    float p1 = acc1 + __shfl(acc1, il | 32, 64);
    if (lane < 32 && act) {
        float r = 1.f / (ssum + 1e-16f);
        float2 bv = ((const float2*)b2)[il];
        float2 o;
        o.x = fmaf(p0, r, bv.x);
        o.y = fmaf(p1, r, bv.y);
        ((float2*)(out + (size_t)n * F2))[il] = o;
    }
}

extern "C" void kernel_launch(void* const* d_in, const int* in_sizes, int n_in,
                              void* d_out, int out_size, void* d_ws, size_t ws_size,
                              hipStream_t stream) {
    const float* x      = (const float*)d_in[0];
    const int*   ei     = (const int*)d_in[1];
    const float* W1     = (const float*)d_in[2];
    const float* a_src1 = (const float*)d_in[3];
    const float* a_dst1 = (const float*)d_in[4];
    const float* b1     = (const float*)d_in[5];
    const float* W2     = (const float*)d_in[6];
    const float* a_src2 = (const float*)d_in[7];
    const float* a_dst2 = (const float*)d_in[8];
    const float* b2     = (const float*)d_in[9];
    float* out = (float*)d_out;
    const int* srcp = ei;            // edge_index[0]
    const int* dstp = ei + E_BASE;   // edge_index[1]

    unsigned* h1b       = (unsigned*)d_ws;                     // N*32 uints (12.8MB)
    uint2*    store     = (uint2*)(h1b + (size_t)NN * 32);     // NB*BCAP uint2 (19.3MB)
    float*    as1       = (float*)(store + (size_t)NB * BCAP); // N*8
    float*    ad1       = as1 + (size_t)NN * H1n;              // N*8
    float*    out1r     = ad1 + (size_t)NN * H1n;              // N*64
    unsigned* h2b       = (unsigned*)(out1r + (size_t)NN * F1);// N*20 uints
    float*    as2       = (float*)(h2b + (size_t)NN * 20);     // N
    float*    ad2       = as2 + NN;                            // N
    int*      row_start = (int*)(ad2 + NN);                    // N+1
    int*      csr_src   = row_start + (NN + 1);                // E_TOT
    int*      bucket_cnt= csr_src + E_TOT;                     // NB
    int*      bucket_base= bucket_cnt + NB;                    // NB+1

    hipMemsetAsync(bucket_cnt, 0, NB * sizeof(int), stream);

    partition<<<P1_BLOCKS, 256, 0, stream>>>(srcp, dstp, bucket_cnt, store);
    bucket_scan<<<1, 64, 0, stream>>>(bucket_cnt, bucket_base, row_start);
    bucket_csr<<<NB, 256, 0, stream>>>(bucket_cnt, bucket_base, store, row_start, csr_src);

    linear1<<<(NN + 63) / 64, 256, 0, stream>>>(x, W1, a_src1, a_dst1, h1b, as1, ad1);
    node_agg1<<<NN, 64, 0, stream>>>(row_start, csr_src, as1, ad1, h1b, b1, out1r);

    linear2<<<(NN + 127) / 128, 256, 0, stream>>>(out1r, W2, a_src2, a_dst2, h2b, as2, ad2);
    node_agg2<<<NN, 64, 0, stream>>>(row_start, csr_src, as2, ad2, h2b, b2, out);
}